// Round 1
// baseline (402.185 us; speedup 1.0000x reference)
//
#include <hip/hip_runtime.h>
#include <math.h>

#define N_NODES 20000
#define N_EDGES 320000
#define ET (N_EDGES + N_NODES)   // with self loops
#define IN_C 512
#define HEADS 8
#define HID 32
#define HH (HEADS * HID)         // 256
#define OUT_C 40
#define NEG_SLOPE 0.2f

// ---------------- GEMM1: h1 = x @ w1 + b1   [20000,512]x[512,256] ----------------
#define BM 64
#define BN 64
#define BK 16
__global__ __launch_bounds__(256) void gemm1_kernel(
    const float* __restrict__ A, const float* __restrict__ B,
    const float* __restrict__ bias, float* __restrict__ C, int M) {
  __shared__ float As[BK][BM + 1];
  __shared__ float Bs[BK][BN];
  const int tid = threadIdx.x;
  const int tx = tid & 15, ty = tid >> 4;
  const int rowBase = blockIdx.y * BM;
  const int colBase = blockIdx.x * BN;
  float acc[4][4] = {};
  const int ar = tid >> 2;          // 0..63 (row in tile)
  const int ac = (tid & 3) * 4;     // 0,4,8,12 (k in tile)
  const int br = tid >> 4;          // 0..15 (k in tile)
  const int bc = (tid & 15) * 4;    // 0..60 (col in tile)
  for (int k0 = 0; k0 < IN_C; k0 += BK) {
    float4 av = make_float4(0.f, 0.f, 0.f, 0.f);
    int arow = rowBase + ar;
    if (arow < M) av = *(const float4*)(A + (size_t)arow * IN_C + k0 + ac);
    As[ac + 0][ar] = av.x; As[ac + 1][ar] = av.y;
    As[ac + 2][ar] = av.z; As[ac + 3][ar] = av.w;
    float4 bv = *(const float4*)(B + (size_t)(k0 + br) * HH + colBase + bc);
    *(float4*)&Bs[br][bc] = bv;
    __syncthreads();
#pragma unroll
    for (int k = 0; k < BK; k++) {
      float a[4], b[4];
#pragma unroll
      for (int i = 0; i < 4; i++) a[i] = As[k][ty * 4 + i];
#pragma unroll
      for (int j = 0; j < 4; j++) b[j] = Bs[k][tx * 4 + j];
#pragma unroll
      for (int i = 0; i < 4; i++)
#pragma unroll
        for (int j = 0; j < 4; j++) acc[i][j] += a[i] * b[j];
    }
    __syncthreads();
  }
#pragma unroll
  for (int i = 0; i < 4; i++) {
    int row = rowBase + ty * 4 + i;
    if (row >= M) continue;
    int col = colBase + tx * 4;
    float4 v = make_float4(acc[i][0] + bias[col + 0], acc[i][1] + bias[col + 1],
                           acc[i][2] + bias[col + 2], acc[i][3] + bias[col + 3]);
    *(float4*)(C + (size_t)row * HH + col) = v;
  }
}

// ---------------- attn1: per-node per-head dot with att vectors ----------------
__global__ __launch_bounds__(256) void attn1_kernel(
    const float* __restrict__ h1, const float* __restrict__ asrc,
    const float* __restrict__ adst, float* __restrict__ as1, float* __restrict__ ad1) {
  int n = blockIdx.x, t = threadIdx.x;       // t = head*32 + c
  float h = h1[(size_t)n * HH + t];
  float ps = h * asrc[t];
  float pd = h * adst[t];
  for (int o = 16; o > 0; o >>= 1) {
    ps += __shfl_down(ps, o, 32);
    pd += __shfl_down(pd, o, 32);
  }
  if ((t & 31) == 0) {
    as1[n * HEADS + (t >> 5)] = ps;
    ad1[n * HEADS + (t >> 5)] = pd;
  }
}

// ---------------- CSR build (by dst) ----------------
__global__ void count_kernel(const int* __restrict__ ei, int* __restrict__ deg) {
  int e = blockIdx.x * blockDim.x + threadIdx.x;
  if (e >= ET) return;
  int dst = (e < N_EDGES) ? ei[N_EDGES + e] : (e - N_EDGES);
  atomicAdd(&deg[dst], 1);
}

__global__ __launch_bounds__(1024) void scan_kernel(
    const int* __restrict__ deg, int* __restrict__ offs, int* __restrict__ cursor) {
  __shared__ int sdata[1024];
  __shared__ int carry;
  int t = threadIdx.x;
  if (t == 0) carry = 0;
  __syncthreads();
  for (int base = 0; base < N_NODES; base += 1024) {
    int i = base + t;
    int v = (i < N_NODES) ? deg[i] : 0;
    sdata[t] = v;
    __syncthreads();
    for (int off = 1; off < 1024; off <<= 1) {
      int add = (t >= off) ? sdata[t - off] : 0;
      __syncthreads();
      sdata[t] += add;
      __syncthreads();
    }
    int inc = sdata[t];
    int exc = inc - v + carry;
    if (i < N_NODES) { offs[i] = exc; cursor[i] = exc; }
    __syncthreads();
    if (t == 1023) carry += inc;
    __syncthreads();
  }
  if (t == 0) offs[N_NODES] = carry;
}

__global__ void fill_kernel(const int* __restrict__ ei, int* __restrict__ cursor,
                            int* __restrict__ csr) {
  int e = blockIdx.x * blockDim.x + threadIdx.x;
  if (e >= ET) return;
  int src, dst;
  if (e < N_EDGES) { src = ei[e]; dst = ei[N_EDGES + e]; }
  else { src = e - N_EDGES; dst = src; }
  int pos = atomicAdd(&cursor[dst], 1);
  csr[pos] = src;
}

// ---------------- agg1: online-softmax aggregation + bias + ELU → h2 ----------------
__global__ __launch_bounds__(256) void agg1_kernel(
    const float* __restrict__ h1, const float* __restrict__ as1,
    const float* __restrict__ ad1, const int* __restrict__ offs,
    const int* __restrict__ csr, const float* __restrict__ b1,
    float* __restrict__ h2) {
  int n = blockIdx.x;
  int t = threadIdx.x;                 // t = head*32 + c
  int head = t >> 5;
  int beg = offs[n], end = offs[n + 1];
  float ad = ad1[n * HEADS + head];
  float m = -INFINITY, l = 0.f, acc = 0.f;
  for (int k = beg; k < end; k++) {
    int src = csr[k];
    float e = as1[src * HEADS + head] + ad;
    e = (e > 0.f) ? e : NEG_SLOPE * e;
    float nm = fmaxf(m, e);
    float sc = __expf(m - nm);         // 0 on first iter (m=-inf)
    float p = __expf(e - nm);
    l = l * sc + p;
    acc = acc * sc + p * h1[(size_t)src * HH + t];
    m = nm;
  }
  float v = acc / (l + 1e-16f) + b1[t];
  v = (v > 0.f) ? v : expm1f(v);       // ELU
  h2[(size_t)n * HH + t] = v;
}

// ---------------- GEMM2: h3 = h2 @ w2 + b2   [20000,256]x[256,40] ----------------
__global__ __launch_bounds__(320) void gemm2_kernel(
    const float* __restrict__ h2, const float* __restrict__ w2,
    const float* __restrict__ b2, float* __restrict__ h3) {
  __shared__ float hs[32 * 257];       // 32 nodes x 256 (pad)
  __shared__ float ws2[HH * OUT_C];    // 256x40
  int t = threadIdx.x;
  int nodeBase = blockIdx.x * 32;
  const float* src = h2 + (size_t)nodeBase * HH;
  for (int idx = t; idx < 32 * 256; idx += 320) {
    int n = idx >> 8, k = idx & 255;
    hs[n * 257 + k] = src[idx];
  }
  for (int idx = t; idx < HH * OUT_C; idx += 320) ws2[idx] = w2[idx];
  __syncthreads();
  int c = t % OUT_C;
  int ng = t / OUT_C;                  // 0..7
  float acc[4] = {0.f, 0.f, 0.f, 0.f};
  for (int k = 0; k < HH; k++) {
    float w = ws2[k * OUT_C + c];
#pragma unroll
    for (int i = 0; i < 4; i++) acc[i] += hs[(ng * 4 + i) * 257 + k] * w;
  }
  float bb = b2[c];
#pragma unroll
  for (int i = 0; i < 4; i++) {
    int n = nodeBase + ng * 4 + i;
    h3[(size_t)n * OUT_C + c] = acc[i] + bb;
  }
}

// ---------------- attn2 ----------------
__global__ __launch_bounds__(64) void attn2_kernel(
    const float* __restrict__ h3, const float* __restrict__ asrc,
    const float* __restrict__ adst, float* __restrict__ as2, float* __restrict__ ad2) {
  int n = blockIdx.x, t = threadIdx.x;
  float h = (t < OUT_C) ? h3[(size_t)n * OUT_C + t] : 0.f;
  float ps = (t < OUT_C) ? h * asrc[t] : 0.f;
  float pd = (t < OUT_C) ? h * adst[t] : 0.f;
  for (int o = 32; o > 0; o >>= 1) {
    ps += __shfl_down(ps, o, 64);
    pd += __shfl_down(pd, o, 64);
  }
  if (t == 0) { as2[n] = ps; ad2[n] = pd; }
}

// ---------------- agg2 + log_softmax → out ----------------
__global__ __launch_bounds__(64) void agg2_kernel(
    const float* __restrict__ h3, const float* __restrict__ as2,
    const float* __restrict__ ad2, const int* __restrict__ offs,
    const int* __restrict__ csr, const float* __restrict__ b2,
    float* __restrict__ out) {
  int n = blockIdx.x;
  int t = threadIdx.x;                 // 64 lanes, 40 active channels
  bool act = (t < OUT_C);
  int beg = offs[n], end = offs[n + 1];
  float ad = ad2[n];
  float m = -INFINITY, l = 0.f, acc = 0.f;
  for (int k = beg; k < end; k++) {
    int src = csr[k];
    float e = as2[src] + ad;
    e = (e > 0.f) ? e : NEG_SLOPE * e;
    float nm = fmaxf(m, e);
    float sc = __expf(m - nm);
    float p = __expf(e - nm);
    l = l * sc + p;
    float hv = act ? h3[(size_t)src * OUT_C + t] : 0.f;
    acc = acc * sc + p * hv;
    m = nm;
  }
  float v = acc / (l + 1e-16f) + (act ? b2[t] : 0.f);
  // log_softmax over the 40 channels (wave-wide reduce; inactive lanes padded)
  float x = act ? v : -INFINITY;
  float mx = x;
  for (int o = 32; o > 0; o >>= 1) mx = fmaxf(mx, __shfl_down(mx, o, 64));
  mx = __shfl(mx, 0, 64);
  float ex = act ? __expf(v - mx) : 0.f;
  float s = ex;
  for (int o = 32; o > 0; o >>= 1) s += __shfl_down(s, o, 64);
  s = __shfl(s, 0, 64);
  if (act) out[(size_t)n * OUT_C + t] = v - mx - logf(s);
}

extern "C" void kernel_launch(void* const* d_in, const int* in_sizes, int n_in,
                              void* d_out, int out_size, void* d_ws, size_t ws_size,
                              hipStream_t stream) {
  const float* x     = (const float*)d_in[0];
  const int*   ei    = (const int*)d_in[1];
  const float* w1    = (const float*)d_in[2];
  const float* asrc1 = (const float*)d_in[3];
  const float* adst1 = (const float*)d_in[4];
  const float* b1    = (const float*)d_in[5];
  const float* w2    = (const float*)d_in[6];
  const float* asrc2 = (const float*)d_in[7];
  const float* adst2 = (const float*)d_in[8];
  const float* b2    = (const float*)d_in[9];
  float* out = (float*)d_out;

  // workspace carve-up (~47 MB)
  float* fw = (float*)d_ws;
  float* h1  = fw;  fw += (size_t)N_NODES * HH;
  float* as1 = fw;  fw += (size_t)N_NODES * HEADS;
  float* ad1 = fw;  fw += (size_t)N_NODES * HEADS;
  float* h2  = fw;  fw += (size_t)N_NODES * HH;
  float* h3  = fw;  fw += (size_t)N_NODES * OUT_C;
  float* as2 = fw;  fw += N_NODES;
  float* ad2 = fw;  fw += N_NODES;
  int* deg    = (int*)fw;
  int* offs   = deg + N_NODES;        // N+1
  int* cursor = offs + N_NODES + 1;
  int* csr    = cursor + N_NODES;     // ET

  hipMemsetAsync(deg, 0, N_NODES * sizeof(int), stream);

  gemm1_kernel<<<dim3(HH / BN, (N_NODES + BM - 1) / BM), 256, 0, stream>>>(x, w1, b1, h1, N_NODES);
  attn1_kernel<<<N_NODES, 256, 0, stream>>>(h1, asrc1, adst1, as1, ad1);
  count_kernel<<<(ET + 255) / 256, 256, 0, stream>>>(ei, deg);
  scan_kernel<<<1, 1024, 0, stream>>>(deg, offs, cursor);
  fill_kernel<<<(ET + 255) / 256, 256, 0, stream>>>(ei, cursor, csr);
  agg1_kernel<<<N_NODES, 256, 0, stream>>>(h1, as1, ad1, offs, csr, b1, h2);
  gemm2_kernel<<<N_NODES / 32, 320, 0, stream>>>(h2, w2, b2, h3);
  attn2_kernel<<<N_NODES, 64, 0, stream>>>(h3, asrc2, adst2, as2, ad2);
  agg2_kernel<<<N_NODES, 64, 0, stream>>>(h3, as2, ad2, offs, csr, b2, out);
}

// Round 2
// 342.376 us; speedup vs baseline: 1.1747x; 1.1747x over previous
//
#include <hip/hip_runtime.h>
#include <hip/hip_bf16.h>
#include <math.h>

#define N_NODES 20000
#define N_EDGES 320000
#define ET (N_EDGES + N_NODES)   // with self loops = 340000
#define IN_C 512
#define HEADS 8
#define HID 32
#define HH (HEADS * HID)         // 256
#define OUT_C 40
#define NEG_SLOPE 0.2f

typedef __attribute__((ext_vector_type(8))) short short8;
typedef __attribute__((ext_vector_type(4))) float floatx4;

static __device__ __forceinline__ unsigned short f2bf(float f) {
  __hip_bfloat16 h = __float2bfloat16(f);
  return *(unsigned short*)&h;
}

// ---------------- convert x -> bf16 ----------------
__global__ __launch_bounds__(256) void convert_x_kernel(
    const float* __restrict__ x, unsigned short* __restrict__ xb) {
  size_t i = ((size_t)blockIdx.x * blockDim.x + threadIdx.x) * 4;
  if (i >= (size_t)N_NODES * IN_C) return;
  float4 v = *(const float4*)(x + i);
  ushort4 o;
  o.x = f2bf(v.x); o.y = f2bf(v.y); o.z = f2bf(v.z); o.w = f2bf(v.w);
  *(ushort4*)(xb + i) = o;
}

// ---------------- convert w1 [512,256] -> bf16 transposed [256,512] ----------------
__global__ __launch_bounds__(256) void convert_w_kernel(
    const float* __restrict__ w1, unsigned short* __restrict__ wbT) {
  int id = blockIdx.x * blockDim.x + threadIdx.x;   // 131072
  if (id >= IN_C * HH) return;
  int k = id >> 8, n = id & 255;                    // coalesced read
  wbT[(size_t)n * IN_C + k] = f2bf(w1[id]);
}

// ---------------- GEMM1 (MFMA bf16): h1 = x @ w1 + b1 ----------------
// A = xb [M,512] bf16 row-major; B^T = wbT [256,512] bf16 row-major.
#define BM 128
#define BN 64
#define BK 32
#define APAD 40   // row stride in shorts (80B, 16B-aligned)
__global__ __launch_bounds__(256) void gemm1_kernel(
    const unsigned short* __restrict__ A, const unsigned short* __restrict__ BT,
    const float* __restrict__ bias, float* __restrict__ C, int M) {
  __shared__ unsigned short As[BM][APAD];   // [128][40]
  __shared__ unsigned short Bs[BN][APAD];   // [64][40]
  const int tid = threadIdx.x;
  const int lane = tid & 63, wave = tid >> 6;
  const int wm = (wave & 1) * 64;           // wave row offset within tile
  const int wn = (wave >> 1) * 32;          // wave col offset within tile
  const int r16 = lane & 15, q = lane >> 4; // MFMA quad
  const int rowBase = blockIdx.y * BM;
  const int colBase = blockIdx.x * BN;
  floatx4 acc[4][2] = {};

  for (int k0 = 0; k0 < IN_C; k0 += BK) {
    // stage A: 128 rows x 32 k = 512 chunks of 8 bf16; 2 per thread
#pragma unroll
    for (int i = 0; i < 2; i++) {
      int c = tid + i * 256;
      int row = c >> 2, kc = (c & 3) * 8;
      int arow = rowBase + row;
      float4 v = make_float4(0.f, 0.f, 0.f, 0.f);
      if (arow < M) v = *(const float4*)(A + (size_t)arow * IN_C + k0 + kc);
      *(float4*)&As[row][kc] = v;
    }
    // stage B: 64 rows x 32 k = 256 chunks; 1 per thread
    {
      int row = tid >> 2, kc = (tid & 3) * 8;
      float4 v = *(const float4*)(BT + (size_t)(colBase + row) * IN_C + k0 + kc);
      *(float4*)&Bs[row][kc] = v;
    }
    __syncthreads();
    short8 afrag[4], bfrag[2];
#pragma unroll
    for (int mt = 0; mt < 4; mt++)
      afrag[mt] = *(const short8*)&As[wm + mt * 16 + r16][q * 8];
#pragma unroll
    for (int nt = 0; nt < 2; nt++)
      bfrag[nt] = *(const short8*)&Bs[wn + nt * 16 + r16][q * 8];
#pragma unroll
    for (int mt = 0; mt < 4; mt++)
#pragma unroll
      for (int nt = 0; nt < 2; nt++)
        acc[mt][nt] = __builtin_amdgcn_mfma_f32_16x16x32_bf16(
            afrag[mt], bfrag[nt], acc[mt][nt], 0, 0, 0);
    __syncthreads();
  }
  // epilogue: C/D layout col=lane&15, row=quad*4+reg
#pragma unroll
  for (int mt = 0; mt < 4; mt++) {
#pragma unroll
    for (int nt = 0; nt < 2; nt++) {
      int col = colBase + wn + nt * 16 + r16;
      float bb = bias[col];
#pragma unroll
      for (int r = 0; r < 4; r++) {
        int row = rowBase + wm + mt * 16 + q * 4 + r;
        if (row < M) C[(size_t)row * HH + col] = acc[mt][nt][r] + bb;
      }
    }
  }
}

// ---------------- attn1: per-node per-head dot with att vectors ----------------
__global__ __launch_bounds__(256) void attn1_kernel(
    const float* __restrict__ h1, const float* __restrict__ asrc,
    const float* __restrict__ adst, float* __restrict__ as1, float* __restrict__ ad1) {
  int n = blockIdx.x, t = threadIdx.x;       // t = head*32 + c
  float h = h1[(size_t)n * HH + t];
  float ps = h * asrc[t];
  float pd = h * adst[t];
  for (int o = 16; o > 0; o >>= 1) {
    ps += __shfl_down(ps, o, 32);
    pd += __shfl_down(pd, o, 32);
  }
  if ((t & 31) == 0) {
    as1[n * HEADS + (t >> 5)] = ps;
    ad1[n * HEADS + (t >> 5)] = pd;
  }
}

// ---------------- CSR build (by dst) ----------------
__global__ void count_kernel(const int* __restrict__ ei, int* __restrict__ deg) {
  int e = blockIdx.x * blockDim.x + threadIdx.x;
  if (e >= ET) return;
  int dst = (e < N_EDGES) ? ei[N_EDGES + e] : (e - N_EDGES);
  atomicAdd(&deg[dst], 1);
}

// one-pass scan: thread-serial segments + wave shuffle scan + 16-wave combine
#define SCAN_PER 20
__global__ __launch_bounds__(1024) void scan_kernel(
    const int* __restrict__ deg, int* __restrict__ offs, int* __restrict__ cursor) {
  __shared__ int wsum[16];
  int t = threadIdx.x;
  int base = t * SCAN_PER;
  int local[SCAN_PER];
  int s = 0;
#pragma unroll
  for (int i = 0; i < SCAN_PER; i++) {
    int idx = base + i;
    int v = (idx < N_NODES) ? deg[idx] : 0;
    local[i] = s;          // exclusive within segment
    s += v;
  }
  int lane = t & 63, w = t >> 6;
  int inc = s;
  for (int o = 1; o < 64; o <<= 1) {
    int u = __shfl_up(inc, o, 64);
    if (lane >= o) inc += u;
  }
  if (lane == 63) wsum[w] = inc;
  __syncthreads();
  if (w == 0 && lane < 16) {
    int v = wsum[lane];
    for (int o = 1; o < 16; o <<= 1) {
      int u = __shfl_up(v, o, 64);
      if (lane >= o) v += u;
    }
    wsum[lane] = v;        // inclusive wave sums
  }
  __syncthreads();
  int waveOff = (w == 0) ? 0 : wsum[w - 1];
  int thrOff = waveOff + inc - s;   // exclusive thread offset
#pragma unroll
  for (int i = 0; i < SCAN_PER; i++) {
    int idx = base + i;
    if (idx < N_NODES) {
      int v = thrOff + local[i];
      offs[idx] = v;
      cursor[idx] = v;
    }
  }
  if (t == 0) offs[N_NODES] = ET;
}

__global__ void fill_kernel(const int* __restrict__ ei, int* __restrict__ cursor,
                            int* __restrict__ csr) {
  int e = blockIdx.x * blockDim.x + threadIdx.x;
  if (e >= ET) return;
  int src, dst;
  if (e < N_EDGES) { src = ei[e]; dst = ei[N_EDGES + e]; }
  else { src = e - N_EDGES; dst = src; }
  int pos = atomicAdd(&cursor[dst], 1);
  csr[pos] = src;
}

// ---------------- agg1: online-softmax aggregation + bias + ELU -> h2 ----------------
__global__ __launch_bounds__(256) void agg1_kernel(
    const float* __restrict__ h1, const float* __restrict__ as1,
    const float* __restrict__ ad1, const int* __restrict__ offs,
    const int* __restrict__ csr, const float* __restrict__ b1,
    float* __restrict__ h2) {
  int n = blockIdx.x;
  int t = threadIdx.x;                 // t = head*32 + c
  int head = t >> 5;
  int beg = offs[n], end = offs[n + 1];
  float ad = ad1[n * HEADS + head];
  float m = -INFINITY, l = 0.f, acc = 0.f;
  for (int k = beg; k < end; k++) {
    int src = csr[k];
    float e = as1[src * HEADS + head] + ad;
    e = (e > 0.f) ? e : NEG_SLOPE * e;
    float nm = fmaxf(m, e);
    float sc = __expf(m - nm);         // 0 on first iter (m=-inf)
    float p = __expf(e - nm);
    l = l * sc + p;
    acc = acc * sc + p * h1[(size_t)src * HH + t];
    m = nm;
  }
  float v = acc / (l + 1e-16f) + b1[t];
  v = (v > 0.f) ? v : expm1f(v);       // ELU
  h2[(size_t)n * HH + t] = v;
}

// ---------------- GEMM2: h3 = h2 @ w2 + b2   [20000,256]x[256,40] ----------------
__global__ __launch_bounds__(320) void gemm2_kernel(
    const float* __restrict__ h2, const float* __restrict__ w2,
    const float* __restrict__ b2, float* __restrict__ h3) {
  __shared__ float hs[32 * 257];       // 32 nodes x 256 (pad)
  __shared__ float ws2[HH * OUT_C];    // 256x40
  int t = threadIdx.x;
  int nodeBase = blockIdx.x * 32;
  const float* src = h2 + (size_t)nodeBase * HH;
  for (int idx = t; idx < 32 * 256; idx += 320) {
    int n = idx >> 8, k = idx & 255;
    hs[n * 257 + k] = src[idx];
  }
  for (int idx = t; idx < HH * OUT_C; idx += 320) ws2[idx] = w2[idx];
  __syncthreads();
  int c = t % OUT_C;
  int ng = t / OUT_C;                  // 0..7
  float acc[4] = {0.f, 0.f, 0.f, 0.f};
  for (int k = 0; k < HH; k++) {
    float w = ws2[k * OUT_C + c];
#pragma unroll
    for (int i = 0; i < 4; i++) acc[i] += hs[(ng * 4 + i) * 257 + k] * w;
  }
  float bb = b2[c];
#pragma unroll
  for (int i = 0; i < 4; i++) {
    int n = nodeBase + ng * 4 + i;
    h3[(size_t)n * OUT_C + c] = acc[i] + bb;
  }
}

// ---------------- attn2 ----------------
__global__ __launch_bounds__(64) void attn2_kernel(
    const float* __restrict__ h3, const float* __restrict__ asrc,
    const float* __restrict__ adst, float* __restrict__ as2, float* __restrict__ ad2) {
  int n = blockIdx.x, t = threadIdx.x;
  float h = (t < OUT_C) ? h3[(size_t)n * OUT_C + t] : 0.f;
  float ps = (t < OUT_C) ? h * asrc[t] : 0.f;
  float pd = (t < OUT_C) ? h * adst[t] : 0.f;
  for (int o = 32; o > 0; o >>= 1) {
    ps += __shfl_down(ps, o, 64);
    pd += __shfl_down(pd, o, 64);
  }
  if (t == 0) { as2[n] = ps; ad2[n] = pd; }
}

// ---------------- agg2 + log_softmax -> out ----------------
__global__ __launch_bounds__(64) void agg2_kernel(
    const float* __restrict__ h3, const float* __restrict__ as2,
    const float* __restrict__ ad2, const int* __restrict__ offs,
    const int* __restrict__ csr, const float* __restrict__ b2,
    float* __restrict__ out) {
  int n = blockIdx.x;
  int t = threadIdx.x;                 // 64 lanes, 40 active channels
  bool act = (t < OUT_C);
  int beg = offs[n], end = offs[n + 1];
  float ad = ad2[n];
  float m = -INFINITY, l = 0.f, acc = 0.f;
  for (int k = beg; k < end; k++) {
    int src = csr[k];
    float e = as2[src] + ad;
    e = (e > 0.f) ? e : NEG_SLOPE * e;
    float nm = fmaxf(m, e);
    float sc = __expf(m - nm);
    float p = __expf(e - nm);
    l = l * sc + p;
    float hv = act ? h3[(size_t)src * OUT_C + t] : 0.f;
    acc = acc * sc + p * hv;
    m = nm;
  }
  float v = acc / (l + 1e-16f) + (act ? b2[t] : 0.f);
  float x = act ? v : -INFINITY;
  float mx = x;
  for (int o = 32; o > 0; o >>= 1) mx = fmaxf(mx, __shfl_down(mx, o, 64));
  mx = __shfl(mx, 0, 64);
  float ex = act ? __expf(v - mx) : 0.f;
  float s = ex;
  for (int o = 32; o > 0; o >>= 1) s += __shfl_down(s, o, 64);
  s = __shfl(s, 0, 64);
  if (act) out[(size_t)n * OUT_C + t] = v - mx - logf(s);
}

extern "C" void kernel_launch(void* const* d_in, const int* in_sizes, int n_in,
                              void* d_out, int out_size, void* d_ws, size_t ws_size,
                              hipStream_t stream) {
  const float* x     = (const float*)d_in[0];
  const int*   ei    = (const int*)d_in[1];
  const float* w1    = (const float*)d_in[2];
  const float* asrc1 = (const float*)d_in[3];
  const float* adst1 = (const float*)d_in[4];
  const float* b1    = (const float*)d_in[5];
  const float* w2    = (const float*)d_in[6];
  const float* asrc2 = (const float*)d_in[7];
  const float* adst2 = (const float*)d_in[8];
  const float* b2    = (const float*)d_in[9];
  float* out = (float*)d_out;

  // workspace carve-up
  float* fw = (float*)d_ws;
  float* h1  = fw;  fw += (size_t)N_NODES * HH;
  float* as1 = fw;  fw += (size_t)N_NODES * HEADS;
  float* ad1 = fw;  fw += (size_t)N_NODES * HEADS;
  float* h2  = fw;  fw += (size_t)N_NODES * HH;
  float* h3  = fw;  fw += (size_t)N_NODES * OUT_C;
  float* as2 = fw;  fw += N_NODES;
  float* ad2 = fw;  fw += N_NODES;
  unsigned short* xb  = (unsigned short*)fw;  fw += (size_t)N_NODES * IN_C / 2;
  unsigned short* wbT = (unsigned short*)fw;  fw += (size_t)IN_C * HH / 2;
  int* deg    = (int*)fw;
  int* offs   = deg + N_NODES;        // N+1
  int* cursor = offs + N_NODES + 1;
  int* csr    = cursor + N_NODES;     // ET

  hipMemsetAsync(deg, 0, N_NODES * sizeof(int), stream);

  convert_x_kernel<<<(N_NODES * IN_C / 4 + 255) / 256, 256, 0, stream>>>(x, xb);
  convert_w_kernel<<<(IN_C * HH + 255) / 256, 256, 0, stream>>>(w1, wbT);
  gemm1_kernel<<<dim3(HH / BN, (N_NODES + BM - 1) / BM), 256, 0, stream>>>(xb, wbT, b1, h1, N_NODES);
  attn1_kernel<<<N_NODES, 256, 0, stream>>>(h1, asrc1, adst1, as1, ad1);
  count_kernel<<<(ET + 255) / 256, 256, 0, stream>>>(ei, deg);
  scan_kernel<<<1, 1024, 0, stream>>>(deg, offs, cursor);
  fill_kernel<<<(ET + 255) / 256, 256, 0, stream>>>(ei, cursor, csr);
  agg1_kernel<<<N_NODES, 256, 0, stream>>>(h1, as1, ad1, offs, csr, b1, h2);
  gemm2_kernel<<<N_NODES / 32, 320, 0, stream>>>(h2, w2, b2, h3);
  attn2_kernel<<<N_NODES, 64, 0, stream>>>(h3, asrc2, adst2, as2, ad2);
  agg2_kernel<<<N_NODES, 64, 0, stream>>>(h3, as2, ad2, offs, csr, b2, out);
}